// Round 1
// baseline (460.240 us; speedup 1.0000x reference)
//
#include <hip/hip_runtime.h>

// RNN: h_t = relu(x_t @ W_ih^T + b_ih + b_hh + h_{t-1} @ W_hh^T); y_t = h_t @ W_out^T + b_out
// B=512, T=2000, D=3, H=50. One wave per batch element; lane i owns output row i.
// Per step: broadcast h_j via v_readlane (j unrolled), fmac against per-lane W_hh row.
// Output projection done per 50-step tile via an LDS transpose (stride 51 = conflict-free).

#define BB 512
#define TT 2000
#define DD 3
#define HH 50
#define TILE 50      // divides TT exactly (40 tiles)
#define HSTR 51      // odd stride -> conflict-free column reads

__device__ __forceinline__ float bcast(float v, int lane) {
    return __int_as_float(__builtin_amdgcn_readlane(__float_as_int(v), lane));
}

__global__ __launch_bounds__(64) void rnn_fused_kernel(
    const float* __restrict__ x,      // [B,T,D]
    const float* __restrict__ W_ih,   // [H,D]
    const float* __restrict__ W_hh,   // [H,H]
    const float* __restrict__ b_ih,   // [H]
    const float* __restrict__ b_hh,   // [H]
    const float* __restrict__ W_out,  // [D,H]
    const float* __restrict__ b_out,  // [D]
    float* __restrict__ out)          // [B,T,D]
{
    const int lane = threadIdx.x;                 // 0..63
    const int b    = blockIdx.x;                  // batch element
    const int row  = (lane < HH) ? lane : (HH - 1);  // clamp idle lanes; they never matter

    // Per-lane weights: row `row` of W_hh (50 VGPRs), W_ih row, combined bias.
    float w[HH];
    #pragma unroll
    for (int j = 0; j < HH; ++j) w[j] = W_hh[row * HH + j];
    const float wi0 = W_ih[row * DD + 0];
    const float wi1 = W_ih[row * DD + 1];
    const float wi2 = W_ih[row * DD + 2];
    const float bias = b_ih[row] + b_hh[row];

    __shared__ float hsT[64 * HSTR];   // h transpose buffer: row = hidden idx (lane), col = step in tile
    __shared__ float wo[3][HH];
    __shared__ float bo[3];
    if (lane < HH) {
        wo[0][lane] = W_out[0 * HH + lane];
        wo[1][lane] = W_out[1 * HH + lane];
        wo[2][lane] = W_out[2 * HH + lane];
    }
    if (lane < 3) bo[lane] = b_out[lane];

    const float* xb = x   + (size_t)b * TT * DD;
    float*       yb = out + (size_t)b * TT * DD;

    float h = 0.0f;

    for (int tile = 0; tile < TT / TILE; ++tile) {
        const int t0 = tile * TILE;

        // Lane l stages x[b, t0+l, 0:3] in registers; broadcast by readlane in the loop.
        float xa = 0.0f, xv = 0.0f, xc = 0.0f;
        if (lane < TILE) {
            const float* xs = xb + (size_t)(t0 + lane) * DD;
            xa = xs[0]; xv = xs[1]; xc = xs[2];
        }
        __syncthreads();  // previous tile's stage-2 reads of hsT complete (also orders wo/bo init)

        #pragma unroll 5
        for (int s = 0; s < TILE; ++s) {
            // xp contribution (3 broadcast terms)
            float x0 = bcast(xa, s);
            float x1 = bcast(xv, s);
            float x2 = bcast(xc, s);
            float a0 = fmaf(wi0, x0, bias);
            float a1 = wi1 * x1;
            float a2 = wi2 * x2;
            float a3 = 0.0f;

            // recurrent matvec: 50 broadcast+fmac pairs, 4 accumulators
            #pragma unroll
            for (int j = 0; j < HH; ++j) {
                float hj = bcast(h, j);
                if      ((j & 3) == 0) a0 = fmaf(w[j], hj, a0);
                else if ((j & 3) == 1) a1 = fmaf(w[j], hj, a1);
                else if ((j & 3) == 2) a2 = fmaf(w[j], hj, a2);
                else                   a3 = fmaf(w[j], hj, a3);
            }
            h = fmaxf((a0 + a1) + (a2 + a3), 0.0f);

            // stash for the output projection (2-way bank alias max -> free)
            hsT[lane * HSTR + s] = h;
        }
        __syncthreads();  // hsT visible to the transpose read pattern

        // Stage 2: lane s computes y[t0+s, 0:3] = W_out · h_{t0+s} + b_out
        if (lane < TILE) {
            float y0 = bo[0], y1 = bo[1], y2 = bo[2];
            #pragma unroll
            for (int i = 0; i < HH; ++i) {
                float hv = hsT[i * HSTR + lane];   // consecutive lanes -> consecutive banks
                y0 = fmaf(wo[0][i], hv, y0);
                y1 = fmaf(wo[1][i], hv, y1);
                y2 = fmaf(wo[2][i], hv, y2);
            }
            float* yp = yb + (size_t)(t0 + lane) * DD;
            yp[0] = y0; yp[1] = y1; yp[2] = y2;
        }
    }
}

extern "C" void kernel_launch(void* const* d_in, const int* in_sizes, int n_in,
                              void* d_out, int out_size, void* d_ws, size_t ws_size,
                              hipStream_t stream) {
    const float* x     = (const float*)d_in[0];
    const float* W_ih  = (const float*)d_in[1];
    const float* W_hh  = (const float*)d_in[2];
    const float* b_ih  = (const float*)d_in[3];
    const float* b_hh  = (const float*)d_in[4];
    const float* W_out = (const float*)d_in[5];
    const float* b_out = (const float*)d_in[6];
    float* out = (float*)d_out;

    rnn_fused_kernel<<<BB, 64, 0, stream>>>(x, W_ih, W_hh, b_ih, b_hh, W_out, b_out, out);
}